// Round 6
// baseline (2524.891 us; speedup 1.0000x reference)
//
#include <hip/hip_runtime.h>
#include <math.h>

#define D_X      1024
#define D_TEXT   768
#define FDIM     1792
#define BATCH    256
#define M_EXP    16
#define HW_TOT   1024   // 32*32

// Output layout (flat f32): gates[4096] | moe_loss[1] | probs[4096] | top_idx[512]
#define OUT_GATES 0
#define OUT_LOSS  4096
#define OUT_PROBS 4097
#define OUT_IDX   8193

#define NCHUNK   4
#define CHK      (D_X / NCHUNK)              // 256 channels per chunk
#define POOL_PER_CHUNK (BATCH * CHK / 4)     // 16384 pool blocks per chunk
#define NBLK_MAIN 224                        // 8 m-tiles x 28 n-tiles
#define NBLK_DEG  224
#define NBLK_POOL (BATCH * D_X / 4)          // 65536
#define GRID_TOTAL (NBLK_MAIN + NBLK_DEG + NBLK_POOL)

// ctr indices: [0..3] pool chunk done-counts, [4] deg done, [5] gate partials done

__device__ __forceinline__ void wait_count(int* c, int target) {
    if (threadIdx.x == 0) {
        int g = 0;
        while (__hip_atomic_load(c, __ATOMIC_ACQUIRE, __HIP_MEMORY_SCOPE_AGENT) < target) {
            __builtin_amdgcn_s_sleep(8);
            if (++g > (1 << 21)) break;   // hang insurance: fail, don't hang
        }
    }
    __syncthreads();
}

__device__ __forceinline__ void signal_release(int* c) {
    __threadfence();                      // make prior normal stores agent-visible
    __syncthreads();
    if (threadIdx.x == 0)
        __hip_atomic_fetch_add(c, 1, __ATOMIC_RELEASE, __HIP_MEMORY_SCOPE_AGENT);
}

__device__ __forceinline__ float gelu_exact(float v) {
    return v * 0.5f * (1.0f + erff(v * 0.70710678118654752440f));
}

// ---------------------------------------------------------------------------
// Mega-kernel: [0,224) main-GEMM consumers | [224,448) deg-GEMM | [448,..) pool
// ---------------------------------------------------------------------------
__global__ __launch_bounds__(256) void mega_kernel(const float* __restrict__ x,
                                                   const float* __restrict__ deg,
                                                   const float* __restrict__ W,
                                                   const float* __restrict__ bias,
                                                   const float* __restrict__ wg,
                                                   float* __restrict__ fused,
                                                   float* __restrict__ pact2,
                                                   float* __restrict__ part,
                                                   int* __restrict__ ctr,
                                                   float* __restrict__ out) {
    __shared__ float smem[6208];   // 24.8 KB -> 6 blocks/CU
    const int bid = blockIdx.x;
    const int tid = threadIdx.x;

    if (bid >= NBLK_MAIN + NBLK_DEG) {
        // ================= pool path (chunk-major order) =================
        const int pb   = bid - (NBLK_MAIN + NBLK_DEG);
        const int q    = pb >> 14;          // / 16384
        const int rem  = pb & 16383;
        const int b    = rem >> 6;
        const int cg   = rem & 63;
        const int w    = tid >> 6;
        const int lane = tid & 63;
        const int c    = q * CHK + cg * 4 + w;
        const float4* xr = reinterpret_cast<const float4*>(x + ((size_t)b * D_X + c) * HW_TOT);
        float s = 0.0f;
#pragma unroll
        for (int k = 0; k < 4; ++k) {
            float4 v = xr[k * 64 + lane];
            s += v.x + v.y + v.z + v.w;
        }
#pragma unroll
        for (int off = 32; off > 0; off >>= 1) s += __shfl_xor(s, off, 64);
        if (lane == 0) {
            // agent-scope store: device-visible once vmcnt-retired (no wbl2 scan)
            __hip_atomic_store(&fused[(size_t)b * D_X + c], s * (1.0f / 1024.0f),
                               __ATOMIC_RELAXED, __HIP_MEMORY_SCOPE_AGENT);
        }
        __syncthreads();   // drains vmcnt -> stores at coherence point
        if (tid == 0)
            __hip_atomic_fetch_add(&ctr[q], 1, __ATOMIC_RELAXED, __HIP_MEMORY_SCOPE_AGENT);
        return;
    }

    if (bid >= NBLK_MAIN) {
        // ================= deg-GEMM path: pact2 = degraded @ W[1024:,:] =====
        float* As1 = smem;               // [32][33]
        float* Ws1 = smem + 32 * 33;     // [32][64]
        const int db = bid - NBLK_MAIN;
        const int m0 = (db / 28) * 32;
        const int n0 = (db % 28) * 64;

        const int tx = tid & 15, ty = tid >> 4;
        const int ar1  = tid >> 3;             // 0..31
        const int ak41 = (tid & 7) * 4;
        const int wk   = tid >> 4;             // rows wk, wk+16
        const int wc41 = (tid & 15) * 4;

        float acc[2][4] = {};
        for (int k0 = 0; k0 < D_TEXT; k0 += 32) {
            const float4 a  = *reinterpret_cast<const float4*>(
                deg + (size_t)(m0 + ar1) * D_TEXT + k0 + ak41);
            const float4 w0 = *reinterpret_cast<const float4*>(
                W + (size_t)(D_X + k0 + wk) * FDIM + n0 + wc41);
            const float4 w1 = *reinterpret_cast<const float4*>(
                W + (size_t)(D_X + k0 + wk + 16) * FDIM + n0 + wc41);
            __syncthreads();
            As1[(ak41 + 0) * 33 + ar1] = a.x; As1[(ak41 + 1) * 33 + ar1] = a.y;
            As1[(ak41 + 2) * 33 + ar1] = a.z; As1[(ak41 + 3) * 33 + ar1] = a.w;
            *reinterpret_cast<float4*>(&Ws1[wk * 64 + wc41])        = w0;
            *reinterpret_cast<float4*>(&Ws1[(wk + 16) * 64 + wc41]) = w1;
            __syncthreads();
#pragma unroll
            for (int kk = 0; kk < 32; ++kk) {
                const float2 a2 = *reinterpret_cast<const float2*>(&As1[kk * 33 + ty * 2]);
                const float4 w4 = *reinterpret_cast<const float4*>(&Ws1[kk * 64 + tx * 4]);
                acc[0][0] = fmaf(a2.x, w4.x, acc[0][0]);
                acc[0][1] = fmaf(a2.x, w4.y, acc[0][1]);
                acc[0][2] = fmaf(a2.x, w4.z, acc[0][2]);
                acc[0][3] = fmaf(a2.x, w4.w, acc[0][3]);
                acc[1][0] = fmaf(a2.y, w4.x, acc[1][0]);
                acc[1][1] = fmaf(a2.y, w4.y, acc[1][1]);
                acc[1][2] = fmaf(a2.y, w4.z, acc[1][2]);
                acc[1][3] = fmaf(a2.y, w4.w, acc[1][3]);
            }
        }
#pragma unroll
        for (int i = 0; i < 2; ++i) {
            float4 v;
            v.x = acc[i][0]; v.y = acc[i][1]; v.z = acc[i][2]; v.w = acc[i][3];
            *reinterpret_cast<float4*>(pact2 + (size_t)(m0 + ty * 2 + i) * FDIM + n0 + tx * 4) = v;
        }
        signal_release(&ctr[4]);
        return;
    }

    // ================= main-GEMM consumer path ==========================
    float* Asm = smem;             // [64][33]
    float* Wsm = smem + 64 * 33;   // [64][64]
    const int nb = bid % 28;
    const int m0 = (bid / 28) * 32;
    const int n0 = nb * 64;

    const int tx = tid & 15, ty = tid >> 4;
    const int ar  = tid >> 4;              // A rows ar, ar+16
    const int ak4 = (tid & 15) * 4;
    const int wr0 = tid >> 4;              // W k-rows wr0,+16,+32,+48
    const int wc4 = (tid & 15) * 4;

    float acc[2][4] = {};

    for (int q = 0; q < NCHUNK; ++q) {
        wait_count(&ctr[q], POOL_PER_CHUNK);
#pragma unroll
        for (int t = 0; t < CHK / 64; ++t) {   // 4 K-iterations of 64
            const int k0 = q * CHK + t * 64;
            const float4 pa0 = *reinterpret_cast<const float4*>(
                fused + (size_t)(m0 + ar) * D_X + k0 + ak4);
            const float4 pa1 = *reinterpret_cast<const float4*>(
                fused + (size_t)(m0 + ar + 16) * D_X + k0 + ak4);
            const float4 pw0 = *reinterpret_cast<const float4*>(
                W + (size_t)(k0 + wr0) * FDIM + n0 + wc4);
            const float4 pw1 = *reinterpret_cast<const float4*>(
                W + (size_t)(k0 + wr0 + 16) * FDIM + n0 + wc4);
            const float4 pw2 = *reinterpret_cast<const float4*>(
                W + (size_t)(k0 + wr0 + 32) * FDIM + n0 + wc4);
            const float4 pw3 = *reinterpret_cast<const float4*>(
                W + (size_t)(k0 + wr0 + 48) * FDIM + n0 + wc4);
            __syncthreads();
            Asm[(ak4 + 0) * 33 + ar] = pa0.x; Asm[(ak4 + 1) * 33 + ar] = pa0.y;
            Asm[(ak4 + 2) * 33 + ar] = pa0.z; Asm[(ak4 + 3) * 33 + ar] = pa0.w;
            Asm[(ak4 + 0) * 33 + ar + 16] = pa1.x; Asm[(ak4 + 1) * 33 + ar + 16] = pa1.y;
            Asm[(ak4 + 2) * 33 + ar + 16] = pa1.z; Asm[(ak4 + 3) * 33 + ar + 16] = pa1.w;
            *reinterpret_cast<float4*>(&Wsm[wr0 * 64 + wc4])        = pw0;
            *reinterpret_cast<float4*>(&Wsm[(wr0 + 16) * 64 + wc4]) = pw1;
            *reinterpret_cast<float4*>(&Wsm[(wr0 + 32) * 64 + wc4]) = pw2;
            *reinterpret_cast<float4*>(&Wsm[(wr0 + 48) * 64 + wc4]) = pw3;
            __syncthreads();
#pragma unroll
            for (int kk = 0; kk < 64; ++kk) {
                const float2 a2 = *reinterpret_cast<const float2*>(&Asm[kk * 33 + ty * 2]);
                const float4 w4 = *reinterpret_cast<const float4*>(&Wsm[kk * 64 + tx * 4]);
                acc[0][0] = fmaf(a2.x, w4.x, acc[0][0]);
                acc[0][1] = fmaf(a2.x, w4.y, acc[0][1]);
                acc[0][2] = fmaf(a2.x, w4.z, acc[0][2]);
                acc[0][3] = fmaf(a2.x, w4.w, acc[0][3]);
                acc[1][0] = fmaf(a2.y, w4.x, acc[1][0]);
                acc[1][1] = fmaf(a2.y, w4.y, acc[1][1]);
                acc[1][2] = fmaf(a2.y, w4.z, acc[1][2]);
                acc[1][3] = fmaf(a2.y, w4.w, acc[1][3]);
            }
        }
    }

    // epilogue: + pact2 (deg half) + bias, exact GELU -> actS; gate partials
    wait_count(&ctr[4], NBLK_DEG);
    float* actS = smem;            // [32][65], aliases Asm (safe: barrier above)
    float* wgs  = smem + 32 * 65;  // [64][16]
#pragma unroll
    for (int i = 0; i < 2; ++i) {
        const int m = ty * 2 + i;
#pragma unroll
        for (int j = 0; j < 4; ++j) {
            const int n = tx * 4 + j;
            const float v = acc[i][j]
                + pact2[(size_t)(m0 + m) * FDIM + n0 + n]
                + bias[n0 + n];
            actS[m * 65 + n] = gelu_exact(v);
        }
    }
    {
        const int r  = tid >> 2;
        const int c4 = (tid & 3) * 4;
        *reinterpret_cast<float4*>(&wgs[r * M_EXP + c4]) =
            *reinterpret_cast<const float4*>(wg + (size_t)(n0 + r) * M_EXP + c4);
    }
    __syncthreads();

    const int pm = tid >> 3;             // 0..31
    const int pe = (tid & 7) * 2;        // 0,2,..,14
    float s0 = 0.0f, s1 = 0.0f;
#pragma unroll
    for (int n = 0; n < 64; ++n) {
        const float a = actS[pm * 65 + n];
        s0 = fmaf(a, wgs[n * M_EXP + pe], s0);
        s1 = fmaf(a, wgs[n * M_EXP + pe + 1], s1);
    }
    float* pr = part + ((size_t)nb * BATCH + m0 + pm) * M_EXP + pe;
    pr[0] = s0;
    pr[1] = s1;
    signal_release(&ctr[5]);

    // ================= finalize (block 0 only) ==========================
    if (bid == 0) {
        wait_count(&ctr[5], NBLK_MAIN);
        const int b = tid;               // 256 threads = 256 rows
        float l[M_EXP];
#pragma unroll
        for (int m = 0; m < M_EXP; ++m) l[m] = 0.0f;
        for (int nb2 = 0; nb2 < FDIM / 64; ++nb2) {
            const float4* prr = reinterpret_cast<const float4*>(
                part + ((size_t)nb2 * BATCH + b) * M_EXP);
#pragma unroll
            for (int qq = 0; qq < 4; ++qq) {
                const float4 v = prr[qq];
                l[qq * 4 + 0] += v.x;
                l[qq * 4 + 1] += v.y;
                l[qq * 4 + 2] += v.z;
                l[qq * 4 + 3] += v.w;
            }
        }
        float mx = l[0];
#pragma unroll
        for (int m = 1; m < M_EXP; ++m) mx = fmaxf(mx, l[m]);
        float e[M_EXP], s = 0.0f;
#pragma unroll
        for (int m = 0; m < M_EXP; ++m) { e[m] = expf(l[m] - mx); s += e[m]; }
        const float inv = 1.0f / s;
#pragma unroll
        for (int m = 0; m < M_EXP; ++m) out[OUT_PROBS + b * M_EXP + m] = e[m] * inv;

        int i0 = 0; float v0 = l[0];
#pragma unroll
        for (int m = 1; m < M_EXP; ++m) if (l[m] > v0) { v0 = l[m]; i0 = m; }
        int i1 = -1; float v1 = -INFINITY;
#pragma unroll
        for (int m = 0; m < M_EXP; ++m) if (m != i0 && l[m] > v1) { v1 = l[m]; i1 = m; }

        const float t = expf(v1 - v0);
        const float g0 = 1.0f / (1.0f + t);
        const float g1 = t * g0;
#pragma unroll
        for (int m = 0; m < M_EXP; ++m) out[OUT_GATES + b * M_EXP + m] = 0.0f;
        out[OUT_GATES + b * M_EXP + i0] = g0;
        out[OUT_GATES + b * M_EXP + i1] = g1;
        out[OUT_IDX + b * 2 + 0] = (float)i0;
        out[OUT_IDX + b * 2 + 1] = (float)i1;
        if (b == 0) out[OUT_LOSS] = 0.0f;
    }
}

// ---------------------------------------------------------------------------
extern "C" void kernel_launch(void* const* d_in, const int* in_sizes, int n_in,
                              void* d_out, int out_size, void* d_ws, size_t ws_size,
                              hipStream_t stream) {
    const float* x        = (const float*)d_in[0];
    const float* degraded = (const float*)d_in[1];
    const float* w_fusion = (const float*)d_in[2];
    const float* b_fusion = (const float*)d_in[3];
    const float* w_gate   = (const float*)d_in[4];
    float* out = (float*)d_out;

    float* fused = (float*)d_ws;                          // 256*1024 f32
    float* pact2 = fused + (size_t)BATCH * D_X;           // 256*1792 f32
    float* part  = pact2 + (size_t)BATCH * FDIM;          // 28*256*16 f32
    int*   ctr   = (int*)(part + (size_t)(FDIM / 64) * BATCH * M_EXP);

    hipMemsetAsync(ctr, 0, 8 * sizeof(int), stream);
    mega_kernel<<<GRID_TOTAL, 256, 0, stream>>>(x, degraded, w_fusion, b_fusion, w_gate,
                                                fused, pact2, part, ctr, out);
}

// Round 7
// 879.369 us; speedup vs baseline: 2.8713x; 2.8713x over previous
//
#include <hip/hip_runtime.h>
#include <math.h>

#define D_X      1024
#define D_TEXT   768
#define FDIM     1792
#define BATCH    256
#define M_EXP    16
#define HW_TOT   1024   // 32*32

// Output layout (flat f32): gates[4096] | moe_loss[1] | probs[4096] | top_idx[512]
#define OUT_GATES 0
#define OUT_LOSS  4096
#define OUT_PROBS 4097
#define OUT_IDX   8193

#define NCHUNK   4
#define CHK      (D_X / NCHUNK)              // 256 channels per chunk
#define ROWS_PER_POOL_BLK 16
#define NBLK_POOL (BATCH * D_X / ROWS_PER_POOL_BLK)   // 16384
#define POOL_PER_CHUNK (NBLK_POOL / NCHUNK)           // 4096
#define NBLK_MAIN 224                        // 8 m-tiles x 28 n-tiles
#define NBLK_DEG  224
#define GRID_TOTAL (NBLK_MAIN + NBLK_DEG + NBLK_POOL)

// ctr: [0..3] pool chunk done-counts, [4] deg done, [5] gate partials done

__device__ __forceinline__ void wait_count(int* c, int target) {
    if (threadIdx.x == 0) {
        int g = 0;
        // RELAXED poll: plain L2 read, no cache-invalidate per iteration.
        while (__hip_atomic_load(c, __ATOMIC_RELAXED, __HIP_MEMORY_SCOPE_AGENT) < target) {
            __builtin_amdgcn_s_sleep(16);
            if (++g > (1 << 20)) break;   // hang insurance: fail, don't hang
        }
        // single acquire for ordering + L1 invalidate, once per wait
        (void)__hip_atomic_load(c, __ATOMIC_ACQUIRE, __HIP_MEMORY_SCOPE_AGENT);
    }
    __syncthreads();
    asm volatile("" ::: "memory");  // no load hoisting above the wait
}

__device__ __forceinline__ void signal_release(int* c) {
    __threadfence();                      // prior stores agent-visible
    __syncthreads();
    if (threadIdx.x == 0)
        __hip_atomic_fetch_add(c, 1, __ATOMIC_RELEASE, __HIP_MEMORY_SCOPE_AGENT);
}

__device__ __forceinline__ float gelu_exact(float v) {
    return v * 0.5f * (1.0f + erff(v * 0.70710678118654752440f));
}

// ---------------------------------------------------------------------------
// Mega-kernel: [0,224) main-GEMM consumers | [224,448) deg-GEMM | [448,..) pool
// LDS = 3104 floats (12.4 KB) -> 8 blocks/CU (thread-limited), full pool occupancy
// ---------------------------------------------------------------------------
__global__ __launch_bounds__(256) void mega_kernel(const float* __restrict__ x,
                                                   const float* __restrict__ deg,
                                                   const float* __restrict__ W,
                                                   const float* __restrict__ bias,
                                                   const float* __restrict__ wg,
                                                   float* __restrict__ fused,
                                                   float* __restrict__ pact2,
                                                   float* __restrict__ part,
                                                   int* __restrict__ ctr,
                                                   float* __restrict__ out) {
    __shared__ float smem[3104];   // 12.4 KB
    const int bid = blockIdx.x;
    const int tid = threadIdx.x;

    if (bid >= NBLK_MAIN + NBLK_DEG) {
        // ================= pool path (chunk-major order) =================
        // block handles 16 channels of one batch row-group: 4 waves x 4 rows
        const int pb   = bid - (NBLK_MAIN + NBLK_DEG);
        const int q    = pb >> 12;          // / 4096
        const int rem  = pb & 4095;
        const int b    = rem >> 4;          // 0..255
        const int rg   = rem & 15;
        const int w    = tid >> 6;
        const int lane = tid & 63;
        const int cbase = q * CHK + rg * 16 + w * 4;
#pragma unroll
        for (int r = 0; r < 4; ++r) {
            const int c = cbase + r;
            const float4* xr = reinterpret_cast<const float4*>(
                x + ((size_t)b * D_X + c) * HW_TOT);
            float s = 0.0f;
#pragma unroll
            for (int k = 0; k < 4; ++k) {
                float4 v = xr[k * 64 + lane];
                s += v.x + v.y + v.z + v.w;
            }
#pragma unroll
            for (int off = 32; off > 0; off >>= 1) s += __shfl_xor(s, off, 64);
            if (lane == 0) {
                // agent-scope store: coherent-point visible once vmcnt-retired
                __hip_atomic_store(&fused[(size_t)b * D_X + c], s * (1.0f / 1024.0f),
                                   __ATOMIC_RELAXED, __HIP_MEMORY_SCOPE_AGENT);
            }
        }
        __syncthreads();   // drains vmcnt -> all stores at coherence point
        if (tid == 0)
            __hip_atomic_fetch_add(&ctr[q], 1, __ATOMIC_RELAXED, __HIP_MEMORY_SCOPE_AGENT);
        return;
    }

    float* As1 = smem;               // [32][33] = 1056
    float* Ws1 = smem + 32 * 33;     // [32][64] = 2048

    if (bid >= NBLK_MAIN) {
        // ================= deg-GEMM path: pact2 = degraded @ W[1024:,:] =====
        const int db = bid - NBLK_MAIN;
        const int m0 = (db / 28) * 32;
        const int n0 = (db % 28) * 64;

        const int tx = tid & 15, ty = tid >> 4;
        const int ar1  = tid >> 3;             // 0..31
        const int ak41 = (tid & 7) * 4;
        const int wk   = tid >> 4;             // rows wk, wk+16
        const int wc41 = (tid & 15) * 4;

        float acc[2][4] = {};
        for (int k0 = 0; k0 < D_TEXT; k0 += 32) {
            const float4 a  = *reinterpret_cast<const float4*>(
                deg + (size_t)(m0 + ar1) * D_TEXT + k0 + ak41);
            const float4 w0 = *reinterpret_cast<const float4*>(
                W + (size_t)(D_X + k0 + wk) * FDIM + n0 + wc41);
            const float4 w1 = *reinterpret_cast<const float4*>(
                W + (size_t)(D_X + k0 + wk + 16) * FDIM + n0 + wc41);
            __syncthreads();
            As1[(ak41 + 0) * 33 + ar1] = a.x; As1[(ak41 + 1) * 33 + ar1] = a.y;
            As1[(ak41 + 2) * 33 + ar1] = a.z; As1[(ak41 + 3) * 33 + ar1] = a.w;
            *reinterpret_cast<float4*>(&Ws1[wk * 64 + wc41])        = w0;
            *reinterpret_cast<float4*>(&Ws1[(wk + 16) * 64 + wc41]) = w1;
            __syncthreads();
#pragma unroll
            for (int kk = 0; kk < 32; ++kk) {
                const float2 a2 = *reinterpret_cast<const float2*>(&As1[kk * 33 + ty * 2]);
                const float4 w4 = *reinterpret_cast<const float4*>(&Ws1[kk * 64 + tx * 4]);
                acc[0][0] = fmaf(a2.x, w4.x, acc[0][0]);
                acc[0][1] = fmaf(a2.x, w4.y, acc[0][1]);
                acc[0][2] = fmaf(a2.x, w4.z, acc[0][2]);
                acc[0][3] = fmaf(a2.x, w4.w, acc[0][3]);
                acc[1][0] = fmaf(a2.y, w4.x, acc[1][0]);
                acc[1][1] = fmaf(a2.y, w4.y, acc[1][1]);
                acc[1][2] = fmaf(a2.y, w4.z, acc[1][2]);
                acc[1][3] = fmaf(a2.y, w4.w, acc[1][3]);
            }
        }
#pragma unroll
        for (int i = 0; i < 2; ++i) {
            float4 v;
            v.x = acc[i][0]; v.y = acc[i][1]; v.z = acc[i][2]; v.w = acc[i][3];
            *reinterpret_cast<float4*>(pact2 + (size_t)(m0 + ty * 2 + i) * FDIM + n0 + tx * 4) = v;
        }
        signal_release(&ctr[4]);
        return;
    }

    // ================= main-GEMM consumer path ==========================
    const int nb = bid % 28;
    const int m0 = (bid / 28) * 32;
    const int n0 = nb * 64;

    const int tx = tid & 15, ty = tid >> 4;
    const int ar1  = tid >> 3;             // 0..31
    const int ak4  = (tid & 7) * 4;
    const int wk   = tid >> 4;             // W k-rows wk, wk+16
    const int wc4  = (tid & 15) * 4;

    float acc[2][4] = {};

    for (int q = 0; q < NCHUNK; ++q) {
        wait_count(&ctr[q], POOL_PER_CHUNK);
        for (int t = 0; t < CHK / 32; ++t) {   // 8 K-iterations of 32
            const int k0 = q * CHK + t * 32;
            const float4 a  = *reinterpret_cast<const float4*>(
                fused + (size_t)(m0 + ar1) * D_X + k0 + ak4);
            const float4 w0 = *reinterpret_cast<const float4*>(
                W + (size_t)(k0 + wk) * FDIM + n0 + wc4);
            const float4 w1 = *reinterpret_cast<const float4*>(
                W + (size_t)(k0 + wk + 16) * FDIM + n0 + wc4);
            __syncthreads();
            As1[(ak4 + 0) * 33 + ar1] = a.x; As1[(ak4 + 1) * 33 + ar1] = a.y;
            As1[(ak4 + 2) * 33 + ar1] = a.z; As1[(ak4 + 3) * 33 + ar1] = a.w;
            *reinterpret_cast<float4*>(&Ws1[wk * 64 + wc4])        = w0;
            *reinterpret_cast<float4*>(&Ws1[(wk + 16) * 64 + wc4]) = w1;
            __syncthreads();
#pragma unroll
            for (int kk = 0; kk < 32; ++kk) {
                const float2 a2 = *reinterpret_cast<const float2*>(&As1[kk * 33 + ty * 2]);
                const float4 w4 = *reinterpret_cast<const float4*>(&Ws1[kk * 64 + tx * 4]);
                acc[0][0] = fmaf(a2.x, w4.x, acc[0][0]);
                acc[0][1] = fmaf(a2.x, w4.y, acc[0][1]);
                acc[0][2] = fmaf(a2.x, w4.z, acc[0][2]);
                acc[0][3] = fmaf(a2.x, w4.w, acc[0][3]);
                acc[1][0] = fmaf(a2.y, w4.x, acc[1][0]);
                acc[1][1] = fmaf(a2.y, w4.y, acc[1][1]);
                acc[1][2] = fmaf(a2.y, w4.z, acc[1][2]);
                acc[1][3] = fmaf(a2.y, w4.w, acc[1][3]);
            }
        }
    }

    // epilogue: + pact2 (deg half) + bias, exact GELU -> actS; gate partials
    wait_count(&ctr[4], NBLK_DEG);      // includes barrier: smem reuse safe
    float* actS = smem;                 // [32][65] = 2080
    float* wgs  = smem + 32 * 65;       // [64][16] = 1024  (total 3104)
#pragma unroll
    for (int i = 0; i < 2; ++i) {
        const int m = ty * 2 + i;
#pragma unroll
        for (int j = 0; j < 4; ++j) {
            const int n = tx * 4 + j;
            const float v = acc[i][j]
                + pact2[(size_t)(m0 + m) * FDIM + n0 + n]
                + bias[n0 + n];
            actS[m * 65 + n] = gelu_exact(v);
        }
    }
    {
        const int r  = tid >> 2;
        const int c4 = (tid & 3) * 4;
        *reinterpret_cast<float4*>(&wgs[r * M_EXP + c4]) =
            *reinterpret_cast<const float4*>(wg + (size_t)(n0 + r) * M_EXP + c4);
    }
    __syncthreads();

    const int pm = tid >> 3;             // 0..31
    const int pe = (tid & 7) * 2;        // 0,2,..,14
    float s0 = 0.0f, s1 = 0.0f;
#pragma unroll
    for (int n = 0; n < 64; ++n) {
        const float a = actS[pm * 65 + n];
        s0 = fmaf(a, wgs[n * M_EXP + pe], s0);
        s1 = fmaf(a, wgs[n * M_EXP + pe + 1], s1);
    }
    float* pr = part + ((size_t)nb * BATCH + m0 + pm) * M_EXP + pe;
    pr[0] = s0;
    pr[1] = s1;
    signal_release(&ctr[5]);

    // ================= finalize (block 0 only) ==========================
    if (bid == 0) {
        wait_count(&ctr[5], NBLK_MAIN);
        const int b = tid;               // 256 threads = 256 rows
        float l[M_EXP];
#pragma unroll
        for (int m = 0; m < M_EXP; ++m) l[m] = 0.0f;
        for (int nb2 = 0; nb2 < FDIM / 64; ++nb2) {
            const float4* prr = reinterpret_cast<const float4*>(
                part + ((size_t)nb2 * BATCH + b) * M_EXP);
#pragma unroll
            for (int qq = 0; qq < 4; ++qq) {
                const float4 v = prr[qq];
                l[qq * 4 + 0] += v.x;
                l[qq * 4 + 1] += v.y;
                l[qq * 4 + 2] += v.z;
                l[qq * 4 + 3] += v.w;
            }
        }
        float mx = l[0];
#pragma unroll
        for (int m = 1; m < M_EXP; ++m) mx = fmaxf(mx, l[m]);
        float e[M_EXP], s = 0.0f;
#pragma unroll
        for (int m = 0; m < M_EXP; ++m) { e[m] = expf(l[m] - mx); s += e[m]; }
        const float inv = 1.0f / s;
#pragma unroll
        for (int m = 0; m < M_EXP; ++m) out[OUT_PROBS + b * M_EXP + m] = e[m] * inv;

        int i0 = 0; float v0 = l[0];
#pragma unroll
        for (int m = 1; m < M_EXP; ++m) if (l[m] > v0) { v0 = l[m]; i0 = m; }
        int i1 = -1; float v1 = -INFINITY;
#pragma unroll
        for (int m = 0; m < M_EXP; ++m) if (m != i0 && l[m] > v1) { v1 = l[m]; i1 = m; }

        const float t = expf(v1 - v0);
        const float g0 = 1.0f / (1.0f + t);
        const float g1 = t * g0;
#pragma unroll
        for (int m = 0; m < M_EXP; ++m) out[OUT_GATES + b * M_EXP + m] = 0.0f;
        out[OUT_GATES + b * M_EXP + i0] = g0;
        out[OUT_GATES + b * M_EXP + i1] = g1;
        out[OUT_IDX + b * 2 + 0] = (float)i0;
        out[OUT_IDX + b * 2 + 1] = (float)i1;
        if (b == 0) out[OUT_LOSS] = 0.0f;
    }
}

// ---------------------------------------------------------------------------
extern "C" void kernel_launch(void* const* d_in, const int* in_sizes, int n_in,
                              void* d_out, int out_size, void* d_ws, size_t ws_size,
                              hipStream_t stream) {
    const float* x        = (const float*)d_in[0];
    const float* degraded = (const float*)d_in[1];
    const float* w_fusion = (const float*)d_in[2];
    const float* b_fusion = (const float*)d_in[3];
    const float* w_gate   = (const float*)d_in[4];
    float* out = (float*)d_out;

    float* fused = (float*)d_ws;                          // 256*1024 f32
    float* pact2 = fused + (size_t)BATCH * D_X;           // 256*1792 f32
    float* part  = pact2 + (size_t)BATCH * FDIM;          // 28*256*16 f32
    int*   ctr   = (int*)(part + (size_t)(FDIM / 64) * BATCH * M_EXP);

    hipMemsetAsync(ctr, 0, 8 * sizeof(int), stream);
    mega_kernel<<<GRID_TOTAL, 256, 0, stream>>>(x, degraded, w_fusion, b_fusion, w_gate,
                                                fused, pact2, part, ctr, out);
}

// Round 8
// 258.519 us; speedup vs baseline: 9.7667x; 3.4016x over previous
//
#include <hip/hip_runtime.h>
#include <math.h>

#define D_X      1024
#define D_TEXT   768
#define FDIM     1792
#define BATCH    256
#define M_EXP    16
#define HW_TOT   1024   // 32*32

// Output layout (flat f32): gates[4096] | moe_loss[1] | probs[4096] | top_idx[512]
#define OUT_GATES 0
#define OUT_LOSS  4096
#define OUT_PROBS 4097
#define OUT_IDX   8193

#define NBLK_DEG    224
#define POOL_BLOCKS 2048
#define GRID1       (NBLK_DEG + POOL_BLOCKS)
#define NROWS       (BATCH * D_X)            // 262144

// ---------------------------------------------------------------------------
// Kernel 1 (role-split):
//   blocks [0, 224):    deg-GEMM  pact2 = degraded @ W[1024:, :]  (R5-proven)
//   blocks [224, 2272): persistent mean-pool, 2 rows/wave/iter (R2-proven)
// ---------------------------------------------------------------------------
__global__ __launch_bounds__(256) void pool_deggemm_kernel(const float* __restrict__ x,
                                                           const float* __restrict__ deg,
                                                           const float* __restrict__ W,
                                                           float* __restrict__ fused,
                                                           float* __restrict__ pact2) {
    __shared__ float As1[32][33];   // deg tile, transposed [k][m]
    __shared__ float Ws1[32][64];   // W tile [k][n]

    const int bid = blockIdx.x;
    const int tid = threadIdx.x;

    if (bid >= NBLK_DEG) {
        // ---- persistent pool: 8192 waves, 32 rows each (16 iters x 2 rows) ----
        const int pb   = bid - NBLK_DEG;
        const int lane = tid & 63;
        const int gw   = pb * 4 + (tid >> 6);          // wave id 0..8191

        for (int r2 = gw * 2; r2 < NROWS; r2 += 2 * 4 * POOL_BLOCKS) {   // stride 16384
            const float4* x0 = reinterpret_cast<const float4*>(x + (size_t)r2 * HW_TOT);
            float4 v0[4], v1[4];
#pragma unroll
            for (int k = 0; k < 4; ++k) v0[k] = x0[k * 64 + lane];
#pragma unroll
            for (int k = 0; k < 4; ++k) v1[k] = x0[256 + k * 64 + lane];
            float s0 = 0.0f, s1 = 0.0f;
#pragma unroll
            for (int k = 0; k < 4; ++k) {
                s0 += v0[k].x + v0[k].y + v0[k].z + v0[k].w;
                s1 += v1[k].x + v1[k].y + v1[k].z + v1[k].w;
            }
#pragma unroll
            for (int off = 32; off > 0; off >>= 1) {
                s0 += __shfl_xor(s0, off, 64);
                s1 += __shfl_xor(s1, off, 64);
            }
            if (lane == 0) {
                float2 st;
                st.x = s0 * (1.0f / 1024.0f);
                st.y = s1 * (1.0f / 1024.0f);
                // fused is dense (256,1024) row-major: index == r2
                *reinterpret_cast<float2*>(&fused[r2]) = st;
            }
        }
        return;
    }

    // ---- deg-GEMM path: 32m x 64n tile, BK=32, 24 iters (verbatim R5) ----
    const int mb = bid / 28;
    const int nb = bid % 28;
    const int m0 = mb * 32;
    const int n0 = nb * 64;

    const int tx = tid & 15;        // n-groups of 4
    const int ty = tid >> 4;        // m-groups of 2

    const int ar  = tid >> 3;       // A row 0..31
    const int ak4 = (tid & 7) * 4;  // A k-col
    const int wk  = tid >> 4;       // W k-row (+16 for second)
    const int wc4 = (tid & 15) * 4; // W n-col

    float acc[2][4] = {};

    for (int k0 = 0; k0 < D_TEXT; k0 += 32) {
        __syncthreads();
        {
            const float4 a = *reinterpret_cast<const float4*>(
                deg + (size_t)(m0 + ar) * D_TEXT + k0 + ak4);
            As1[ak4 + 0][ar] = a.x; As1[ak4 + 1][ar] = a.y;
            As1[ak4 + 2][ar] = a.z; As1[ak4 + 3][ar] = a.w;
            *reinterpret_cast<float4*>(&Ws1[wk][wc4]) =
                *reinterpret_cast<const float4*>(W + (size_t)(D_X + k0 + wk) * FDIM + n0 + wc4);
            *reinterpret_cast<float4*>(&Ws1[wk + 16][wc4]) =
                *reinterpret_cast<const float4*>(W + (size_t)(D_X + k0 + wk + 16) * FDIM + n0 + wc4);
        }
        __syncthreads();
#pragma unroll
        for (int kk = 0; kk < 32; ++kk) {
            const float2 a = *reinterpret_cast<const float2*>(&As1[kk][ty * 2]);
            const float4 w = *reinterpret_cast<const float4*>(&Ws1[kk][tx * 4]);
            acc[0][0] = fmaf(a.x, w.x, acc[0][0]);
            acc[0][1] = fmaf(a.x, w.y, acc[0][1]);
            acc[0][2] = fmaf(a.x, w.z, acc[0][2]);
            acc[0][3] = fmaf(a.x, w.w, acc[0][3]);
            acc[1][0] = fmaf(a.y, w.x, acc[1][0]);
            acc[1][1] = fmaf(a.y, w.y, acc[1][1]);
            acc[1][2] = fmaf(a.y, w.z, acc[1][2]);
            acc[1][3] = fmaf(a.y, w.w, acc[1][3]);
        }
    }

#pragma unroll
    for (int i = 0; i < 2; ++i) {
        float4 v;
        v.x = acc[i][0]; v.y = acc[i][1]; v.z = acc[i][2]; v.w = acc[i][3];
        *reinterpret_cast<float4*>(pact2 + (size_t)(m0 + ty * 2 + i) * FDIM + n0 + tx * 4) = v;
    }
}

// ---------------------------------------------------------------------------
// Kernel 2: act = gelu(fused @ W[:1024] + pact2 + bias) tile, gate partials.
// (verbatim R5: BK=64, 2x4/thread, reg-staged dbuf LDS, acc init from pact2)
// ---------------------------------------------------------------------------
#define BM 32
#define BN 64
#define BK 64
#define KDIM D_X            // 1024
#define NITER (KDIM / BK)   // 16

#define LOADA(k0)                                                                     \
    pa0 = *reinterpret_cast<const float4*>(A + (size_t)(m0 + ar) * KDIM + (k0) + ak4);       \
    pa1 = *reinterpret_cast<const float4*>(A + (size_t)(m0 + ar + 16) * KDIM + (k0) + ak4);

#define LOADW(k0)                                                                     \
    pw0 = *reinterpret_cast<const float4*>(W + (size_t)((k0) + wr0) * FDIM + n0 + wc4);      \
    pw1 = *reinterpret_cast<const float4*>(W + (size_t)((k0) + wr0 + 16) * FDIM + n0 + wc4); \
    pw2 = *reinterpret_cast<const float4*>(W + (size_t)((k0) + wr0 + 32) * FDIM + n0 + wc4); \
    pw3 = *reinterpret_cast<const float4*>(W + (size_t)((k0) + wr0 + 48) * FDIM + n0 + wc4);

#define STOREA(buf)                                                                   \
    As[buf][ak4 + 0][ar] = pa0.x; As[buf][ak4 + 1][ar] = pa0.y;                       \
    As[buf][ak4 + 2][ar] = pa0.z; As[buf][ak4 + 3][ar] = pa0.w;                       \
    As[buf][ak4 + 0][ar + 16] = pa1.x; As[buf][ak4 + 1][ar + 16] = pa1.y;             \
    As[buf][ak4 + 2][ar + 16] = pa1.z; As[buf][ak4 + 3][ar + 16] = pa1.w;

#define STOREW(buf)                                                                   \
    *reinterpret_cast<float4*>(&Ws[buf][wr0][wc4])      = pw0;                        \
    *reinterpret_cast<float4*>(&Ws[buf][wr0 + 16][wc4]) = pw1;                        \
    *reinterpret_cast<float4*>(&Ws[buf][wr0 + 32][wc4]) = pw2;                        \
    *reinterpret_cast<float4*>(&Ws[buf][wr0 + 48][wc4]) = pw3;

__global__ __launch_bounds__(256) void gemm_gate_kernel(const float* __restrict__ A,
                                                        const float* __restrict__ W,
                                                        const float* __restrict__ pact2,
                                                        const float* __restrict__ bias,
                                                        const float* __restrict__ wg,
                                                        float* __restrict__ part) {
    __shared__ float As[2][BK][BM + 1];
    __shared__ float Ws[2][BK][BN];
    __shared__ float wgs[BN][M_EXP];
    __shared__ float actS[BM][BN + 1];

    const int tid = threadIdx.x;
    const int tx = tid & 15;
    const int ty = tid >> 4;
    const int m0 = blockIdx.x * BM;
    const int n0 = blockIdx.y * BN;

    // wg slab: 64 rows x 16 = 256 float4
    {
        const int r  = tid >> 2;
        const int c4 = (tid & 3) * 4;
        *reinterpret_cast<float4*>(&wgs[r][c4]) =
            *reinterpret_cast<const float4*>(wg + (size_t)(n0 + r) * M_EXP + c4);
    }

    const int ar  = tid >> 4;
    const int ak4 = (tid & 15) * 4;
    const int wr0 = tid >> 4;
    const int wc4 = (tid & 15) * 4;

    float4 pa0, pa1, pw0, pw1, pw2, pw3;

    LOADA(0); LOADW(0);
    STOREA(0); STOREW(0);
    LOADA(BK); LOADW(BK);

    // acc init from deg-GEMM partial
    float acc[2][4];
    {
        const float4 i0 = *reinterpret_cast<const float4*>(
            pact2 + (size_t)(m0 + ty * 2) * FDIM + n0 + tx * 4);
        const float4 i1 = *reinterpret_cast<const float4*>(
            pact2 + (size_t)(m0 + ty * 2 + 1) * FDIM + n0 + tx * 4);
        acc[0][0] = i0.x; acc[0][1] = i0.y; acc[0][2] = i0.z; acc[0][3] = i0.w;
        acc[1][0] = i1.x; acc[1][1] = i1.y; acc[1][2] = i1.z; acc[1][3] = i1.w;
    }
    __syncthreads();

    int cur = 0;
    for (int t = 0; t < NITER; ++t) {
#pragma unroll
        for (int kk = 0; kk < BK; ++kk) {
            const float2 a = *reinterpret_cast<const float2*>(&As[cur][kk][ty * 2]);
            const float4 w = *reinterpret_cast<const float4*>(&Ws[cur][kk][tx * 4]);
            acc[0][0] = fmaf(a.x, w.x, acc[0][0]);
            acc[0][1] = fmaf(a.x, w.y, acc[0][1]);
            acc[0][2] = fmaf(a.x, w.z, acc[0][2]);
            acc[0][3] = fmaf(a.x, w.w, acc[0][3]);
            acc[1][0] = fmaf(a.y, w.x, acc[1][0]);
            acc[1][1] = fmaf(a.y, w.y, acc[1][1]);
            acc[1][2] = fmaf(a.y, w.z, acc[1][2]);
            acc[1][3] = fmaf(a.y, w.w, acc[1][3]);
        }
        if (t < NITER - 1) {
            const int nxt = cur ^ 1;
            STOREA(nxt); STOREW(nxt);
            if (t < NITER - 2) {
                const int k0 = (t + 2) * BK;
                LOADA(k0); LOADW(k0);
            }
            __syncthreads();
            cur = nxt;
        }
    }

    // epilogue: bias + exact GELU -> actS
#pragma unroll
    for (int i = 0; i < 2; ++i) {
        const int m = ty * 2 + i;
#pragma unroll
        for (int j = 0; j < 4; ++j) {
            const int n = tx * 4 + j;
            const float v = acc[i][j] + bias[n0 + n];
            actS[m][n] = v * 0.5f * (1.0f + erff(v * 0.70710678118654752440f));
        }
    }
    __syncthreads();

    // gate partials: 32 rows x 16 experts, 2 per thread
    const int pm = tid >> 3;
    const int pe = (tid & 7) * 2;
    float s0 = 0.0f, s1 = 0.0f;
#pragma unroll
    for (int n = 0; n < BN; ++n) {
        const float a = actS[pm][n];
        s0 = fmaf(a, wgs[n][pe], s0);
        s1 = fmaf(a, wgs[n][pe + 1], s1);
    }
    float* pr = part + ((size_t)blockIdx.y * BATCH + m0 + pm) * M_EXP + pe;
    pr[0] = s0;
    pr[1] = s1;
}

// ---------------------------------------------------------------------------
// Kernel 3: finalize — sum 28 partials (fixed order), softmax, top-2 routing.
// ---------------------------------------------------------------------------
#define NNB (FDIM / BN)   // 28

__global__ __launch_bounds__(64) void finalize_kernel(const float* __restrict__ part,
                                                      float* __restrict__ out) {
    const int b = blockIdx.x * 64 + threadIdx.x;   // 0..255

    float l[M_EXP];
#pragma unroll
    for (int m = 0; m < M_EXP; ++m) l[m] = 0.0f;

    for (int nb = 0; nb < NNB; ++nb) {
        const float4* pr = reinterpret_cast<const float4*>(part + ((size_t)nb * BATCH + b) * M_EXP);
#pragma unroll
        for (int q = 0; q < 4; ++q) {
            const float4 v = pr[q];
            l[q * 4 + 0] += v.x;
            l[q * 4 + 1] += v.y;
            l[q * 4 + 2] += v.z;
            l[q * 4 + 3] += v.w;
        }
    }

    float mx = l[0];
#pragma unroll
    for (int m = 1; m < M_EXP; ++m) mx = fmaxf(mx, l[m]);
    float e[M_EXP], s = 0.0f;
#pragma unroll
    for (int m = 0; m < M_EXP; ++m) { e[m] = expf(l[m] - mx); s += e[m]; }
    const float inv = 1.0f / s;
#pragma unroll
    for (int m = 0; m < M_EXP; ++m) out[OUT_PROBS + b * M_EXP + m] = e[m] * inv;

    int i0 = 0; float v0 = l[0];
#pragma unroll
    for (int m = 1; m < M_EXP; ++m) if (l[m] > v0) { v0 = l[m]; i0 = m; }
    int i1 = -1; float v1 = -INFINITY;
#pragma unroll
    for (int m = 0; m < M_EXP; ++m) if (m != i0 && l[m] > v1) { v1 = l[m]; i1 = m; }

    const float t = expf(v1 - v0);
    const float g0 = 1.0f / (1.0f + t);
    const float g1 = t * g0;

#pragma unroll
    for (int m = 0; m < M_EXP; ++m) out[OUT_GATES + b * M_EXP + m] = 0.0f;
    out[OUT_GATES + b * M_EXP + i0] = g0;
    out[OUT_GATES + b * M_EXP + i1] = g1;

    out[OUT_IDX + b * 2 + 0] = (float)i0;
    out[OUT_IDX + b * 2 + 1] = (float)i1;

    if (b == 0) out[OUT_LOSS] = 0.0f;
}

// ---------------------------------------------------------------------------
extern "C" void kernel_launch(void* const* d_in, const int* in_sizes, int n_in,
                              void* d_out, int out_size, void* d_ws, size_t ws_size,
                              hipStream_t stream) {
    const float* x        = (const float*)d_in[0];
    const float* degraded = (const float*)d_in[1];
    const float* w_fusion = (const float*)d_in[2];
    const float* b_fusion = (const float*)d_in[3];
    const float* w_gate   = (const float*)d_in[4];
    float* out = (float*)d_out;

    float* fused = (float*)d_ws;                          // 256*1024 f32 (dense)
    float* pact2 = fused + (size_t)BATCH * D_X;           // 256*1792 f32
    float* part  = pact2 + (size_t)BATCH * FDIM;          // 28*256*16 f32

    // 1) deg-GEMM (blocks 0..223) + persistent pool (blocks 224..2271)
    pool_deggemm_kernel<<<GRID1, 256, 0, stream>>>(x, degraded, w_fusion, fused, pact2);

    // 2) main GEMM K in [0,1024) + bias + gelu + gate partials: grid (8, 28)
    gemm_gate_kernel<<<dim3(BATCH / BM, FDIM / BN), 256, 0, stream>>>(fused, w_fusion, pact2,
                                                                     b_fusion, w_gate, part);

    // 3) finalize
    finalize_kernel<<<BATCH / 64, 64, 0, stream>>>(part, out);
}

// Round 9
// 234.507 us; speedup vs baseline: 10.7668x; 1.1024x over previous
//
#include <hip/hip_runtime.h>
#include <math.h>

#define D_X      1024
#define D_TEXT   768
#define FDIM     1792
#define BATCH    256
#define M_EXP    16
#define HW_TOT   1024   // 32*32

// Output layout (flat f32): gates[4096] | moe_loss[1] | probs[4096] | top_idx[512]
#define OUT_GATES 0
#define OUT_LOSS  4096
#define OUT_PROBS 4097
#define OUT_IDX   8193

#define NBLK_DGEMM 224
#define NBLK_POOL  (BATCH * D_X / 4)   // 65536

// ---------------------------------------------------------------------------
// Kernel 1 (verbatim R5 champion):
//   blocks [0, 224):      deg-GEMM  pact2 = degraded @ W[1024:, :]
//   blocks [224, 65760):  one-shot mean-pool, one wave per (b,c) row
// ---------------------------------------------------------------------------
__global__ __launch_bounds__(256) void pool_deggemm_kernel(const float* __restrict__ x,
                                                           const float* __restrict__ deg,
                                                           const float* __restrict__ W,
                                                           float* __restrict__ fused,
                                                           float* __restrict__ pact2) {
    __shared__ float As1[32][33];   // deg tile, transposed [k][m]
    __shared__ float Ws1[32][64];   // W tile [k][n]

    const int bid = blockIdx.x;
    const int tid = threadIdx.x;

    if (bid >= NBLK_DGEMM) {
        // ---- pool path: one wave per (b,c) row of 1024 contiguous floats ----
        const int gtid = (bid - NBLK_DGEMM) * 256 + tid;
        const int row  = gtid >> 6;            // 0 .. 262143
        const int lane = gtid & 63;
        const float4* xr = reinterpret_cast<const float4*>(x + (size_t)row * HW_TOT);
        float s = 0.0f;
#pragma unroll
        for (int k = 0; k < 4; ++k) {
            float4 v = xr[k * 64 + lane];
            s += v.x + v.y + v.z + v.w;
        }
#pragma unroll
        for (int off = 32; off > 0; off >>= 1) s += __shfl_xor(s, off, 64);
        if (lane == 0) fused[row] = s * (1.0f / 1024.0f);   // fused dense (256,1024)
        return;
    }

    // ---- deg-GEMM path: 32m x 64n tile, BK=32, 24 iters ----
    const int mb = bid / 28;
    const int nb = bid % 28;
    const int m0 = mb * 32;
    const int n0 = nb * 64;

    const int tx = tid & 15;        // n-groups of 4
    const int ty = tid >> 4;        // m-groups of 2

    const int ar  = tid >> 3;       // A row 0..31
    const int ak4 = (tid & 7) * 4;  // A k-col
    const int wk  = tid >> 4;       // W k-row (+16 for second)
    const int wc4 = (tid & 15) * 4; // W n-col

    float acc[2][4] = {};

    for (int k0 = 0; k0 < D_TEXT; k0 += 32) {
        __syncthreads();
        {
            const float4 a = *reinterpret_cast<const float4*>(
                deg + (size_t)(m0 + ar) * D_TEXT + k0 + ak4);
            As1[ak4 + 0][ar] = a.x; As1[ak4 + 1][ar] = a.y;
            As1[ak4 + 2][ar] = a.z; As1[ak4 + 3][ar] = a.w;
            *reinterpret_cast<float4*>(&Ws1[wk][wc4]) =
                *reinterpret_cast<const float4*>(W + (size_t)(D_X + k0 + wk) * FDIM + n0 + wc4);
            *reinterpret_cast<float4*>(&Ws1[wk + 16][wc4]) =
                *reinterpret_cast<const float4*>(W + (size_t)(D_X + k0 + wk + 16) * FDIM + n0 + wc4);
        }
        __syncthreads();
#pragma unroll
        for (int kk = 0; kk < 32; ++kk) {
            const float2 a = *reinterpret_cast<const float2*>(&As1[kk][ty * 2]);
            const float4 w = *reinterpret_cast<const float4*>(&Ws1[kk][tx * 4]);
            acc[0][0] = fmaf(a.x, w.x, acc[0][0]);
            acc[0][1] = fmaf(a.x, w.y, acc[0][1]);
            acc[0][2] = fmaf(a.x, w.z, acc[0][2]);
            acc[0][3] = fmaf(a.x, w.w, acc[0][3]);
            acc[1][0] = fmaf(a.y, w.x, acc[1][0]);
            acc[1][1] = fmaf(a.y, w.y, acc[1][1]);
            acc[1][2] = fmaf(a.y, w.z, acc[1][2]);
            acc[1][3] = fmaf(a.y, w.w, acc[1][3]);
        }
    }

#pragma unroll
    for (int i = 0; i < 2; ++i) {
        float4 v;
        v.x = acc[i][0]; v.y = acc[i][1]; v.z = acc[i][2]; v.w = acc[i][3];
        *reinterpret_cast<float4*>(pact2 + (size_t)(m0 + ty * 2 + i) * FDIM + n0 + tx * 4) = v;
    }
}

// ---------------------------------------------------------------------------
// Kernel 2: main GEMM (K in [0,1024), wave-K-split) + bias + GELU + gate
// partials + last-block finalize.
// Staging identical to R5 (BK=64 dbuf, reg-staged). Consumption: wave w owns
// kk in [w*16, w*16+16); per-lane 4m x 8n partial acc; fixed-order LDS reduce.
// ---------------------------------------------------------------------------
#define BM 32
#define BN 64
#define BK 64
#define KDIM D_X            // 1024
#define NITER (KDIM / BK)   // 16
#define ASTR 36             // padded A row stride (16B-aligned rows)

// smem phase A: As[2][64][36] @0 (4608 f), Ws[2][64][64] @4608 (8192 f) = 12800 f
// smem phase B: pacc[4][32][64] @0 (8192 f), actS[32][65] @8192 (2080 f),
//               wgs[64][16] @10272 (1024 f)
#define AS(buf, k, m) As[(buf) * 2304 + (k) * ASTR + (m)]
#define WS(buf, k, n) Ws[(buf) * 4096 + (k) * 64 + (n)]
#define PACC(w, m, n) smem[(w) * 2048 + (m) * 64 + (n)]
#define ACTS(m, n)    smem[8192 + (m) * 65 + (n)]
#define WGS(n, e)     smem[10272 + (n) * M_EXP + (e)]

#define LOADA(k0)                                                                            \
    pa0 = *reinterpret_cast<const float4*>(A + (size_t)(m0 + ar) * KDIM + (k0) + ak4);       \
    pa1 = *reinterpret_cast<const float4*>(A + (size_t)(m0 + ar + 16) * KDIM + (k0) + ak4);

#define LOADW(k0)                                                                            \
    pw0 = *reinterpret_cast<const float4*>(W + (size_t)((k0) + wr0) * FDIM + n0 + wc4);      \
    pw1 = *reinterpret_cast<const float4*>(W + (size_t)((k0) + wr0 + 16) * FDIM + n0 + wc4); \
    pw2 = *reinterpret_cast<const float4*>(W + (size_t)((k0) + wr0 + 32) * FDIM + n0 + wc4); \
    pw3 = *reinterpret_cast<const float4*>(W + (size_t)((k0) + wr0 + 48) * FDIM + n0 + wc4);

#define STOREA(buf)                                                                          \
    AS(buf, ak4 + 0, ar) = pa0.x; AS(buf, ak4 + 1, ar) = pa0.y;                              \
    AS(buf, ak4 + 2, ar) = pa0.z; AS(buf, ak4 + 3, ar) = pa0.w;                              \
    AS(buf, ak4 + 0, ar + 16) = pa1.x; AS(buf, ak4 + 1, ar + 16) = pa1.y;                    \
    AS(buf, ak4 + 2, ar + 16) = pa1.z; AS(buf, ak4 + 3, ar + 16) = pa1.w;

#define STOREW(buf)                                                                          \
    *reinterpret_cast<float4*>(&WS(buf, wr0, wc4))      = pw0;                               \
    *reinterpret_cast<float4*>(&WS(buf, wr0 + 16, wc4)) = pw1;                               \
    *reinterpret_cast<float4*>(&WS(buf, wr0 + 32, wc4)) = pw2;                               \
    *reinterpret_cast<float4*>(&WS(buf, wr0 + 48, wc4)) = pw3;

__global__ __launch_bounds__(256) void gemm_gate_kernel(const float* __restrict__ A,
                                                        const float* __restrict__ W,
                                                        const float* __restrict__ pact2,
                                                        const float* __restrict__ bias,
                                                        const float* __restrict__ wg,
                                                        float* __restrict__ part,
                                                        int* __restrict__ done,
                                                        float* __restrict__ out) {
    __shared__ float smem[12800];
    __shared__ int isLast;
    float* As = smem;
    float* Ws = smem + 4608;

    const int tid = threadIdx.x;
    const int m0 = blockIdx.x * BM;
    const int n0 = blockIdx.y * BN;

    // staging maps (R5)
    const int ar  = tid >> 4;             // A rows ar, ar+16
    const int ak4 = (tid & 15) * 4;
    const int wr0 = tid >> 4;             // W k-rows wr0,+16,+32,+48
    const int wc4 = (tid & 15) * 4;

    // consumption map: wave-K-split, per-lane 4m x 8n
    const int wv   = tid >> 6;            // wave 0..3 -> kk in [wv*16, wv*16+16)
    const int lane = tid & 63;
    const int mg   = lane >> 3;           // m = mg*4 + i
    const int ng   = lane & 7;            // n = ng*8 + j

    float4 pa0, pa1, pw0, pw1, pw2, pw3;

    LOADA(0); LOADW(0);
    STOREA(0); STOREW(0);
    LOADA(BK); LOADW(BK);
    __syncthreads();

    float acc[4][8] = {};
    int cur = 0;

    for (int t = 0; t < NITER; ++t) {
#pragma unroll
        for (int s = 0; s < 16; ++s) {
            const int kk = wv * 16 + s;
            const float4 a  = *reinterpret_cast<const float4*>(&AS(cur, kk, mg * 4));
            const float4 w0 = *reinterpret_cast<const float4*>(&WS(cur, kk, ng * 8));
            const float4 w1 = *reinterpret_cast<const float4*>(&WS(cur, kk, ng * 8 + 4));
            const float av[4] = {a.x, a.y, a.z, a.w};
            const float wvv[8] = {w0.x, w0.y, w0.z, w0.w, w1.x, w1.y, w1.z, w1.w};
#pragma unroll
            for (int i = 0; i < 4; ++i)
#pragma unroll
                for (int j = 0; j < 8; ++j)
                    acc[i][j] = fmaf(av[i], wvv[j], acc[i][j]);
        }
        if (t < NITER - 1) {
            const int nxt = cur ^ 1;
            STOREA(nxt); STOREW(nxt);
            if (t < NITER - 2) {
                const int k0 = (t + 2) * BK;
                LOADA(k0); LOADW(k0);
            }
            __syncthreads();
            cur = nxt;
        }
    }

    // ---- phase B: wave-partial reduce + epilogue (smem re-purposed) ----
    __syncthreads();   // all consumption done before overwriting As/Ws

    // each thread stores its 4x8 partial; wgs loaded into disjoint region
#pragma unroll
    for (int i = 0; i < 4; ++i) {
        float4 v0, v1;
        v0.x = acc[i][0]; v0.y = acc[i][1]; v0.z = acc[i][2]; v0.w = acc[i][3];
        v1.x = acc[i][4]; v1.y = acc[i][5]; v1.z = acc[i][6]; v1.w = acc[i][7];
        *reinterpret_cast<float4*>(&PACC(wv, mg * 4 + i, ng * 8))     = v0;
        *reinterpret_cast<float4*>(&PACC(wv, mg * 4 + i, ng * 8 + 4)) = v1;
    }
    {
        const int r  = tid >> 2;
        const int c4 = (tid & 3) * 4;
        *reinterpret_cast<float4*>(&WGS(r, c4)) =
            *reinterpret_cast<const float4*>(wg + (size_t)(n0 + r) * M_EXP + c4);
    }
    __syncthreads();

    // reduce 4 wave-partials (fixed order) + pact2 + bias, exact GELU -> actS
    {
        const int m   = tid >> 3;            // 0..31
        const int nb8 = (tid & 7) * 8;       // 0..56
#pragma unroll
        for (int h = 0; h < 2; ++h) {
            const int n = nb8 + h * 4;
            const float4 p  = *reinterpret_cast<const float4*>(
                pact2 + (size_t)(m0 + m) * FDIM + n0 + n);
            const float4 bb = *reinterpret_cast<const float4*>(bias + n0 + n);
            const float pv[4] = {p.x, p.y, p.z, p.w};
            const float bv[4] = {bb.x, bb.y, bb.z, bb.w};
#pragma unroll
            for (int j = 0; j < 4; ++j) {
                const float v = ((PACC(0, m, n + j) + PACC(1, m, n + j))
                               + (PACC(2, m, n + j) + PACC(3, m, n + j)))
                               + pv[j] + bv[j];
                ACTS(m, n + j) = v * 0.5f * (1.0f + erff(v * 0.70710678118654752440f));
            }
        }
    }
    __syncthreads();

    // gate partials: 32 rows x 16 experts, 2 per thread (R5)
    const int pm = tid >> 3;
    const int pe = (tid & 7) * 2;
    float s0 = 0.0f, s1 = 0.0f;
#pragma unroll
    for (int n = 0; n < BN; ++n) {
        const float a = ACTS(pm, n);
        s0 = fmaf(a, WGS(n, pe), s0);
        s1 = fmaf(a, WGS(n, pe + 1), s1);
    }
    float* pr = part + ((size_t)blockIdx.y * BATCH + m0 + pm) * M_EXP + pe;
    pr[0] = s0;
    pr[1] = s1;

    // ---- last-block finalize (no polling; single ACQ_REL RMW per block) ----
    __threadfence();          // make this block's part stores agent-visible
    __syncthreads();          // all threads' stores+fences complete
    if (tid == 0) {
        const int prev = __hip_atomic_fetch_add(done, 1, __ATOMIC_ACQ_REL,
                                                __HIP_MEMORY_SCOPE_AGENT);
        isLast = (prev == 8 * 28 - 1);
    }
    __syncthreads();
    if (!isLast) return;

    // winner block: sum 28 partials per row (fixed order), softmax, top-2
    {
        const int b = tid;    // 256 threads = 256 rows
        float l[M_EXP];
#pragma unroll
        for (int m = 0; m < M_EXP; ++m) l[m] = 0.0f;
        for (int nb2 = 0; nb2 < FDIM / BN; ++nb2) {
            const float4* prr = reinterpret_cast<const float4*>(
                part + ((size_t)nb2 * BATCH + b) * M_EXP);
#pragma unroll
            for (int q = 0; q < 4; ++q) {
                const float4 v = prr[q];
                l[q * 4 + 0] += v.x;
                l[q * 4 + 1] += v.y;
                l[q * 4 + 2] += v.z;
                l[q * 4 + 3] += v.w;
            }
        }
        float mx = l[0];
#pragma unroll
        for (int m = 1; m < M_EXP; ++m) mx = fmaxf(mx, l[m]);
        float e[M_EXP], s = 0.0f;
#pragma unroll
        for (int m = 0; m < M_EXP; ++m) { e[m] = expf(l[m] - mx); s += e[m]; }
        const float inv = 1.0f / s;
#pragma unroll
        for (int m = 0; m < M_EXP; ++m) out[OUT_PROBS + b * M_EXP + m] = e[m] * inv;

        int i0 = 0; float v0 = l[0];
#pragma unroll
        for (int m = 1; m < M_EXP; ++m) if (l[m] > v0) { v0 = l[m]; i0 = m; }
        int i1 = -1; float v1 = -INFINITY;
#pragma unroll
        for (int m = 0; m < M_EXP; ++m) if (m != i0 && l[m] > v1) { v1 = l[m]; i1 = m; }

        const float t = expf(v1 - v0);
        const float g0 = 1.0f / (1.0f + t);
        const float g1 = t * g0;
#pragma unroll
        for (int m = 0; m < M_EXP; ++m) out[OUT_GATES + b * M_EXP + m] = 0.0f;
        out[OUT_GATES + b * M_EXP + i0] = g0;
        out[OUT_GATES + b * M_EXP + i1] = g1;
        out[OUT_IDX + b * 2 + 0] = (float)i0;
        out[OUT_IDX + b * 2 + 1] = (float)i1;
        if (b == 0) out[OUT_LOSS] = 0.0f;
    }
}

// ---------------------------------------------------------------------------
extern "C" void kernel_launch(void* const* d_in, const int* in_sizes, int n_in,
                              void* d_out, int out_size, void* d_ws, size_t ws_size,
                              hipStream_t stream) {
    const float* x        = (const float*)d_in[0];
    const float* degraded = (const float*)d_in[1];
    const float* w_fusion = (const float*)d_in[2];
    const float* b_fusion = (const float*)d_in[3];
    const float* w_gate   = (const float*)d_in[4];
    float* out = (float*)d_out;

    float* fused = (float*)d_ws;                          // 256*1024 f32 (dense)
    float* pact2 = fused + (size_t)BATCH * D_X;           // 256*1792 f32
    float* part  = pact2 + (size_t)BATCH * FDIM;          // 28*256*16 f32
    int*   done  = (int*)(part + (size_t)28 * BATCH * M_EXP);

    hipMemsetAsync(done, 0, sizeof(int), stream);

    // 1) deg-GEMM (blocks 0..223) + one-shot pool (blocks 224..65759)
    pool_deggemm_kernel<<<NBLK_DGEMM + NBLK_POOL, 256, 0, stream>>>(x, degraded, w_fusion,
                                                                   fused, pact2);

    // 2) main GEMM + gelu + gate partials + last-block finalize: grid (8, 28)
    gemm_gate_kernel<<<dim3(BATCH / BM, FDIM / BN), 256, 0, stream>>>(fused, w_fusion, pact2,
                                                                     b_fusion, w_gate, part,
                                                                     done, out);
}